// Round 1
// 121.509 us; speedup vs baseline: 1.0085x; 1.0085x over previous
//
#include <hip/hip_runtime.h>
#include <math.h>

#define BB 4
#define TT 128
#define DD 768
#define HD 770
#define HP 800
#define LL 40
#define TP1 129

typedef __attribute__((ext_vector_type(8))) short s16x8;
typedef __attribute__((ext_vector_type(4))) float f32x4;

// ws float offsets
#define P_OFF   0
#define Q_OFF   409600          // 512*800
#define W2F_OFF 819200          // 4800 uint4 = 19200 u32
#define ACC_OFF 838400          // 160 floats

// round-half-up bf16 pair pack; bit-identical to
// ((a+0x8000)>>16) | ((b+0x8000)&0xffff0000), but 3 VALU ops via v_perm_b32
__device__ __forceinline__ unsigned pkperm(float a, float b) {
    unsigned ya = __float_as_uint(a) + 0x8000u;
    unsigned yb = __float_as_uint(b) + 0x8000u;
    return __builtin_amdgcn_perm(yb, ya, 0x07060302u);
}
// RNE bf16 pair pack; bit-identical to rne1(a) | (rne1(b)<<16)
__device__ __forceinline__ unsigned rnepair(float a, float b) {
    unsigned xa = __float_as_uint(a), xb = __float_as_uint(b);
    unsigned ya = xa + 0x7fffu + ((xa >> 16) & 1u);
    unsigned yb = xb + 0x7fffu + ((xb >> 16) & 1u);
    return __builtin_amdgcn_perm(yb, ya, 0x07060302u);
}

// ====== kA: fused prep + X@{W1a,W1b} GEMM, B-frags in LDS ======
__global__ __launch_bounds__(256) void kA(const float* __restrict__ hidden,
                                          const float* __restrict__ W1,
                                          const float* __restrict__ W2,
                                          const float* __restrict__ b1,
                                          float* __restrict__ P,
                                          float* __restrict__ Q,
                                          unsigned* __restrict__ W2f,
                                          float* __restrict__ accum) {
    __shared__ uint4 Bl[3072];   // 48 KB: [half 0..1][ks 0..23][lane 0..63]
    const int bx  = blockIdx.x;
    const int tid = threadIdx.x;

    if (bx < 392) {
        const int nt = bx / 8;          // 0..48
        const int mg = bx - nt * 8;     // 0..7
        const int lane = tid & 63;
        const int col  = lane & 15;
        const int quad = lane >> 4;

        for (int u = tid; u < 3072; u += 256) {
            int half = u / 1536;
            int rem  = u - half * 1536;
            int ks = rem >> 6;
            int ln = rem & 63;
            int kbase = ks * 32 + ((ln >> 4) << 3);
            int h = nt * 16 + (ln & 15);
            int row0 = half * DD + kbase;
            unsigned pk[4];
            #pragma unroll
            for (int sp = 0; sp < 4; ++sp) {
                float v0 = (h < HD) ? W1[(size_t)(row0 + 2 * sp) * HD + h] : 0.0f;
                float v1 = (h < HD) ? W1[(size_t)(row0 + 2 * sp + 1) * HD + h] : 0.0f;
                pk[sp] = rnepair(v0, v1);
            }
            Bl[u] = make_uint4(pk[0], pk[1], pk[2], pk[3]);
        }
        __syncthreads();

        const int mband = mg * 4 + (tid >> 6);   // 0..31
        const int b  = mband >> 3;
        const int tt = mband & 7;

        const float* __restrict__ Arow =
            hidden + (size_t)(b * TP1 + 1 + tt * 16 + col) * DD + (quad << 3);

        f32x4 a0 = (f32x4){0.f, 0.f, 0.f, 0.f};
        f32x4 a1 = (f32x4){0.f, 0.f, 0.f, 0.f};

        #pragma unroll 4
        for (int ks = 0; ks < 24; ++ks) {
            float4 x0 = *(const float4*)(Arow + ks * 32);
            float4 x1 = *(const float4*)(Arow + ks * 32 + 4);
            union { unsigned u[4]; s16x8 v; } af;
            af.u[0] = pkperm(x0.x, x0.y); af.u[1] = pkperm(x0.z, x0.w);
            af.u[2] = pkperm(x1.x, x1.y); af.u[3] = pkperm(x1.z, x1.w);
            union { uint4 q; s16x8 v; } bf0, bf1;
            bf0.q = Bl[ks * 64 + lane];
            bf1.q = Bl[1536 + ks * 64 + lane];
            a0 = __builtin_amdgcn_mfma_f32_16x16x32_bf16(af.v, bf0.v, a0, 0, 0, 0);
            a1 = __builtin_amdgcn_mfma_f32_16x16x32_bf16(af.v, bf1.v, a1, 0, 0, 0);
        }

        const int h = nt * 16 + col;
        if (h < HD) {
            const float bv = b1[h];
            #pragma unroll
            for (int r = 0; r < 4; ++r) {
                int t = tt * 16 + quad * 4 + r;
                size_t row = (size_t)(b * TT + t) * HP;
                P[row + h] = a0[r] + bv;
                Q[row + h] = a1[r];
            }
        }
    } else if (bx < 411) {
        int u = (bx - 392) * 256 + tid;
        if (u >= 4800) return;
        int nt = u / 1600;
        int rem = u - nt * 1600;
        int ks = rem >> 6;
        int ln = rem & 63;
        int kbase = ks * 32 + ((ln >> 4) << 3);
        int l = nt * 16 + (ln & 15);
        unsigned pk[4];
        #pragma unroll
        for (int sp = 0; sp < 4; ++sp) {
            int k0 = kbase + 2 * sp;
            float v0 = (k0 < HD && l < LL)     ? W2[k0 * LL + l]       : 0.0f;
            float v1 = (k0 + 1 < HD && l < LL) ? W2[(k0 + 1) * LL + l] : 0.0f;
            pk[sp] = rnepair(v0, v1);
        }
        ((uint4*)W2f)[u] = make_uint4(pk[0], pk[1], pk[2], pk[3]);
    } else if (bx == 411) {
        if (tid < 160) accum[tid] = 0.0f;
    } else {
        int u = (bx - 412) * 256 + tid;       // < 15360
        int row = u / 30;
        int h = HD + (u - row * 30);          // [770,800)
        Q[(size_t)row * HP + h] = 0.0f;
    }
}

// ====== kB: LDS-staged S-tile MFMA, 2-deep Q register prefetch ======
// Dataflow proof for barrier removal: wave w MFMA-reads Sb rows
// [32w, 32w+32) (arow0 = (wave*32 + lane&15)*20, af1 at +16 rows);
// row j is written by threads {2j, 2j+1}, i.e. rows [32w, 32w+32) are
// written exactly by threads [64w, 64w+64) = wave w. All Sb traffic is
// wave-local -> the per-chunk s_barrier is pure overhead. Same-wave
// cross-lane LDS RAW is handled by the in-order DS pipe; wave_barrier()
// pins compiler ordering at zero runtime cost.
__global__ __launch_bounds__(256) void kB(const float* __restrict__ P,
                                          const float* __restrict__ Q,
                                          const float* __restrict__ W1,
                                          const unsigned* __restrict__ W2f,
                                          const float* __restrict__ b2,
                                          const int* __restrict__ spans,
                                          const int* __restrict__ avail,
                                          float* __restrict__ out,
                                          float* __restrict__ accum) {
    __shared__ unsigned Sb[2][128 * 20];
    __shared__ float var[3 * HP];
    __shared__ int avi[TT];
    __shared__ float sred[192];

    const int i = blockIdx.x;
    const int b = blockIdx.y;
    const int tid = threadIdx.x;
    const int wave = tid >> 6;
    const int lane = tid & 63;

    const int start = spans[b * 2];
    const int end   = spans[b * 2 + 1];

    const int jS = tid >> 1;
    const int hh = (tid & 1) << 4;    // h-offset within 32-chunk: 0 or 16
    int indS;
    {
        bool isfull = (i == start) && (jS == end);
        bool inside = (start <= i) && (i <= jS) && (jS <= end) && !isfull;
        indS = isfull ? 2 : (inside ? 1 : 0);
    }

    {
        const float* Pi  = P + (size_t)(b * TT + i) * HP;
        const float* w1L = W1 + (size_t)2 * DD * HD;
        for (int h = tid; h < HP; h += 256) {
            float pv = (h < HD) ? Pi[h] : 0.0f;
            float wv = (h < HD) ? w1L[h] : 0.0f;
            var[h]        = pv;
            var[HP + h]   = pv + wv;
            var[2*HP + h] = pv + wv + wv;
        }
        if (tid < TT) avi[tid] = avail[i * TT + tid];
    }

    const float* Qj = Q + (size_t)(b * TT + jS) * HP;
    const float* vb = var + indS * HP;

    auto relu4 = [](f32x4 v) {
        f32x4 r;
        r[0] = fmaxf(v[0], 0.f); r[1] = fmaxf(v[1], 0.f);
        r[2] = fmaxf(v[2], 0.f); r[3] = fmaxf(v[3], 0.f);
        return r;
    };
    // pack 16 h (this thread's half of chunk c) into Sb[p].
    // vector adds -> v_pk_add_f32; pkperm -> 3-op bf16 pair pack (bit-identical)
    auto pack2 = [&](int c, int p, f32x4 qa, f32x4 qb, f32x4 qc, f32x4 qd) {
        const int h0 = c * 32 + hh;
        const f32x4* vp = (const f32x4*)(vb + h0);
        f32x4 s0 = relu4(vp[0] + qa);
        f32x4 s1 = relu4(vp[1] + qb);
        f32x4 s2 = relu4(vp[2] + qc);
        f32x4 s3 = relu4(vp[3] + qd);
        uint4* dst = (uint4*)(&Sb[p][jS * 20 + (hh >> 1)]);
        dst[0] = make_uint4(pkperm(s0[0], s0[1]), pkperm(s0[2], s0[3]),
                            pkperm(s1[0], s1[1]), pkperm(s1[2], s1[3]));
        dst[1] = make_uint4(pkperm(s2[0], s2[1]), pkperm(s2[2], s2[3]),
                            pkperm(s3[0], s3[1]), pkperm(s3[2], s3[3]));
    };

    f32x4 acc[2][3];
    #pragma unroll
    for (int mt = 0; mt < 2; ++mt)
        #pragma unroll
        for (int nt = 0; nt < 3; ++nt)
            acc[mt][nt] = (f32x4){0.f, 0.f, 0.f, 0.f};

    // prologue: load chunk 0, pack, issue chunk-1 loads, barrier
    f32x4 ca, cb, cc, cd;   // next-chunk Q (prefetch buffer)
    {
        const f32x4* qp = (const f32x4*)(Qj + hh);
        f32x4 a0 = qp[0], a1 = qp[1], a2 = qp[2], a3 = qp[3];
        pack2(0, 0, a0, a1, a2, a3);
        const f32x4* qn = (const f32x4*)(Qj + 32 + hh);
        ca = qn[0]; cb = qn[1]; cc = qn[2]; cd = qn[3];
    }
    __syncthreads();   // one full barrier: covers var/avi staging (cross-wave)

    const int arow0 = (wave * 32 + (lane & 15)) * 20 + ((lane >> 4) << 2);
    #pragma unroll
    for (int c = 0; c < 25; ++c) {
        const int p = c & 1;
        s16x8 bf0 = *(const s16x8*)((const unsigned*)W2f + (( 0 + c) * 64 + lane) * 4);
        s16x8 bf1 = *(const s16x8*)((const unsigned*)W2f + ((25 + c) * 64 + lane) * 4);
        s16x8 bf2 = *(const s16x8*)((const unsigned*)W2f + ((50 + c) * 64 + lane) * 4);
        s16x8 af0 = *(const s16x8*)(&Sb[p][arow0]);
        s16x8 af1 = *(const s16x8*)(&Sb[p][arow0 + 16 * 20]);
        if (c + 1 < 25) {
            f32x4 fa = ca, fb = cb, fc = cc, fd = cd;
            if (c + 2 < 25) {   // issue loads for c+2 (independent of fa..fd)
                const f32x4* qn = (const f32x4*)(Qj + (c + 2) * 32 + hh);
                ca = qn[0]; cb = qn[1]; cc = qn[2]; cd = qn[3];
            }
            pack2(c + 1, p ^ 1, fa, fb, fc, fd);
        }
        acc[0][0] = __builtin_amdgcn_mfma_f32_16x16x32_bf16(af0, bf0, acc[0][0], 0, 0, 0);
        acc[0][1] = __builtin_amdgcn_mfma_f32_16x16x32_bf16(af0, bf1, acc[0][1], 0, 0, 0);
        acc[0][2] = __builtin_amdgcn_mfma_f32_16x16x32_bf16(af0, bf2, acc[0][2], 0, 0, 0);
        acc[1][0] = __builtin_amdgcn_mfma_f32_16x16x32_bf16(af1, bf0, acc[1][0], 0, 0, 0);
        acc[1][1] = __builtin_amdgcn_mfma_f32_16x16x32_bf16(af1, bf1, acc[1][1], 0, 0, 0);
        acc[1][2] = __builtin_amdgcn_mfma_f32_16x16x32_bf16(af1, bf2, acc[1][2], 0, 0, 0);
        // zero-runtime-cost ordering fences (replaces 25x s_barrier):
        __builtin_amdgcn_wave_barrier();
        __builtin_amdgcn_sched_barrier(0);
    }

    float bias[3];
    #pragma unroll
    for (int nt = 0; nt < 3; ++nt) {
        int l = nt * 16 + (lane & 15);
        bias[nt] = (l < LL) ? b2[l] : 0.0f;
    }
    const int jr0 = wave * 32 + ((lane >> 4) << 2);
    float sE[3] = {0.f, 0.f, 0.f};
    #pragma unroll
    for (int mt = 0; mt < 2; ++mt) {
        #pragma unroll
        for (int r = 0; r < 4; ++r) {
            int j = jr0 + mt * 16 + r;
            bool msk = avi[j] >= 1;
            size_t rowoff = ((size_t)(b * (TT * TT) + i * TT + j)) * LL;
            #pragma unroll
            for (int nt = 0; nt < 3; ++nt) {
                int l = nt * 16 + (lane & 15);
                if (l < LL) {
                    float val = msk ? (acc[mt][nt][r] + bias[nt]) : 0.0f;
                    out[rowoff + l] = val;
                    sE[nt] += __expf(val);
                }
            }
        }
    }
    #pragma unroll
    for (int nt = 0; nt < 3; ++nt) {
        float v = sE[nt];
        v += __shfl_xor(v, 16);
        v += __shfl_xor(v, 32);
        if (lane < 16) sred[wave * 48 + nt * 16 + lane] = v;
    }
    __syncthreads();
    if (tid < 48) {
        float t4 = sred[tid] + sred[48 + tid] + sred[96 + tid] + sred[144 + tid];
        if (tid < LL) atomicAdd(&accum[b * LL + tid], t4);
    }
}

// ================= kD: out -= log(denom) =================
__global__ __launch_bounds__(256) void kD(float* __restrict__ out,
                                          const float* __restrict__ accum) {
    const int idx = blockIdx.x * 256 + threadIdx.x;
    const int e = idx * 4;
    const int b = e / (TT * TT * LL);
    const int l = e % LL;
    float4 v = ((float4*)out)[idx];
    const float* ac = accum + b * LL + l;
    v.x -= __logf(ac[0]); v.y -= __logf(ac[1]);
    v.z -= __logf(ac[2]); v.w -= __logf(ac[3]);
    ((float4*)out)[idx] = v;
}

extern "C" void kernel_launch(void* const* d_in, const int* in_sizes, int n_in,
                              void* d_out, int out_size, void* d_ws, size_t ws_size,
                              hipStream_t stream) {
    const float* hidden = (const float*)d_in[0];
    const float* W1     = (const float*)d_in[1];
    const float* b1     = (const float*)d_in[2];
    const float* W2     = (const float*)d_in[3];
    const float* b2     = (const float*)d_in[4];
    const int*   spans  = (const int*)d_in[5];
    const int*   avail  = (const int*)d_in[6];
    float* out = (float*)d_out;
    float* ws  = (float*)d_ws;

    float*    P     = ws + P_OFF;
    float*    Q     = ws + Q_OFF;
    unsigned* W2f   = (unsigned*)(ws + W2F_OFF);
    float*    accum = ws + ACC_OFF;

    kA <<<dim3(472),    dim3(256), 0, stream>>>(hidden, W1, W2, b1, P, Q, W2f, accum);
    kB <<<dim3(TT, BB), dim3(256), 0, stream>>>(P, Q, W1, W2f, b2, spans, avail, out, accum);
    kD <<<dim3(2560),   dim3(256), 0, stream>>>(out, accum);
}